// Round 2
// baseline (67.428 us; speedup 1.0000x reference)
//
#include <hip/hip_runtime.h>

#define NCLS 10
#define NTHREADS 1024

// Closed-form contrastive loss:
//   loss = 4 * sum_c (n_c*Q_c - S_c^2) - 2 * (N*Q - S^2)
// where S_c/Q_c/n_c are per-class sum, sum-of-squares, count.
__global__ __launch_bounds__(NTHREADS) void closs_kernel(
        const float* __restrict__ p, const int* __restrict__ lbl,
        float* __restrict__ out, int n) {
    float s[NCLS], q[NCLS], cnt[NCLS];
#pragma unroll
    for (int c = 0; c < NCLS; ++c) { s[c] = 0.f; q[c] = 0.f; cnt[c] = 0.f; }

    // Grid is 1 block; stride over the N elements.
    for (int i = threadIdx.x; i < n; i += NTHREADS) {
        float v = p[i];
        int c = lbl[i];
        // Branchless per-class accumulation (compile-time indices only,
        // so the arrays stay in VGPRs — runtime indexing would spill to scratch).
#pragma unroll
        for (int k = 0; k < NCLS; ++k) {
            bool m = (c == k);
            s[k]   += m ? v : 0.0f;
            q[k]   += m ? v * v : 0.0f;
            cnt[k] += m ? 1.0f : 0.0f;
        }
    }

    // 64-lane wave reduction of the 30 accumulators.
#pragma unroll
    for (int c = 0; c < NCLS; ++c) {
#pragma unroll
        for (int off = 32; off > 0; off >>= 1) {
            s[c]   += __shfl_down(s[c], off);
            q[c]   += __shfl_down(q[c], off);
            cnt[c] += __shfl_down(cnt[c], off);
        }
    }

    __shared__ float red[NTHREADS / 64][3 * NCLS];
    const int wave = threadIdx.x >> 6;
    const int lane = threadIdx.x & 63;
    if (lane == 0) {
#pragma unroll
        for (int c = 0; c < NCLS; ++c) {
            red[wave][c]            = s[c];
            red[wave][NCLS + c]     = q[c];
            red[wave][2 * NCLS + c] = cnt[c];
        }
    }
    __syncthreads();

    if (threadIdx.x == 0) {
        float sc[NCLS], qc[NCLS], nc[NCLS];
#pragma unroll
        for (int c = 0; c < NCLS; ++c) { sc[c] = 0.f; qc[c] = 0.f; nc[c] = 0.f; }
        for (int w = 0; w < NTHREADS / 64; ++w) {
#pragma unroll
            for (int c = 0; c < NCLS; ++c) {
                sc[c] += red[w][c];
                qc[c] += red[w][NCLS + c];
                nc[c] += red[w][2 * NCLS + c];
            }
        }
        float S = 0.f, Q = 0.f, acc = 0.f;
#pragma unroll
        for (int c = 0; c < NCLS; ++c) {
            S += sc[c];
            Q += qc[c];
            acc += nc[c] * qc[c] - sc[c] * sc[c];
        }
        const float fn = (float)n;
        out[0] = 4.0f * acc - 2.0f * (fn * Q - S * S);
    }
}

extern "C" void kernel_launch(void* const* d_in, const int* in_sizes, int n_in,
                              void* d_out, int out_size, void* d_ws, size_t ws_size,
                              hipStream_t stream) {
    const float* p  = (const float*)d_in[0];
    const int* lbl  = (const int*)d_in[1];
    float* out      = (float*)d_out;
    const int n     = in_sizes[0];
    closs_kernel<<<1, NTHREADS, 0, stream>>>(p, lbl, out, n);
}

// Round 3
// 63.429 us; speedup vs baseline: 1.0630x; 1.0630x over previous
//
#include <hip/hip_runtime.h>

#define NCLS 10
#define NT 256            // 4 waves — minimizes cross-lane reduction cost
#define NWAVES (NT / 64)

// Closed-form contrastive loss:
//   loss = 4 * sum_c (n_c*Q_c - S_c^2) - 2 * (N*Q - S^2)
// with S_c/Q_c/n_c the per-class sum, sum-of-squares, count.
__global__ __launch_bounds__(NT) void closs_kernel(
        const float* __restrict__ p, const int* __restrict__ lbl,
        float* __restrict__ out, int n) {
    float s[NCLS], q[NCLS];
    unsigned cw[NCLS];     // wave-uniform (ballot/popcount) -> SGPR resident
#pragma unroll
    for (int k = 0; k < NCLS; ++k) { s[k] = 0.f; q[k] = 0.f; cw[k] = 0u; }

    const int tid = threadIdx.x;

    // 8 iterations x float4/int4, fully coalesced (16 B/lane), all loads independent.
#pragma unroll
    for (int j = 0; j < 8; ++j) {
        const int e = (j * NT + tid) * 4;
        if (e + 3 < n) {
            const float4 v4 = *reinterpret_cast<const float4*>(p + e);
            const int4   c4 = *reinterpret_cast<const int4*>(lbl + e);
            const float v[4] = {v4.x, v4.y, v4.z, v4.w};
            const int   c[4] = {c4.x, c4.y, c4.z, c4.w};
#pragma unroll
            for (int u = 0; u < 4; ++u) {
#pragma unroll
                for (int k = 0; k < NCLS; ++k) {
                    const bool m = (c[u] == k);
                    s[k] += m ? v[u] : 0.f;
                    q[k] += m ? v[u] * v[u] : 0.f;
                    // wave-uniform count on the scalar pipe (s_bcnt1_b64 + s_add)
                    cw[k] += (unsigned)__popcll(__ballot(m));
                }
            }
        }
    }

    // Butterfly reduce the 20 float accumulators across the 64-lane wave.
#pragma unroll
    for (int k = 0; k < NCLS; ++k) {
#pragma unroll
        for (int off = 32; off > 0; off >>= 1) {
            s[k] += __shfl_xor(s[k], off);
            q[k] += __shfl_xor(q[k], off);
        }
    }

    __shared__ float redf[NWAVES][2 * NCLS];
    __shared__ unsigned redc[NWAVES][NCLS];
    const int wave = tid >> 6;
    const int lane = tid & 63;
    if (lane == 0) {
#pragma unroll
        for (int k = 0; k < NCLS; ++k) {
            redf[wave][k]        = s[k];
            redf[wave][NCLS + k] = q[k];
            redc[wave][k]        = cw[k];
        }
    }
    __syncthreads();

    if (tid == 0) {
        float S = 0.f, Q = 0.f, acc = 0.f;
#pragma unroll
        for (int k = 0; k < NCLS; ++k) {
            float sk = 0.f, qk = 0.f, nk = 0.f;
            for (int w = 0; w < NWAVES; ++w) {
                sk += redf[w][k];
                qk += redf[w][NCLS + k];
                nk += (float)redc[w][k];
            }
            S += sk;
            Q += qk;
            acc += nk * qk - sk * sk;
        }
        const float fn = (float)n;
        out[0] = 4.0f * acc - 2.0f * (fn * Q - S * S);
    }
}

extern "C" void kernel_launch(void* const* d_in, const int* in_sizes, int n_in,
                              void* d_out, int out_size, void* d_ws, size_t ws_size,
                              hipStream_t stream) {
    const float* p = (const float*)d_in[0];
    const int* lbl = (const int*)d_in[1];
    float* out     = (float*)d_out;
    const int n    = in_sizes[0];
    closs_kernel<<<1, NT, 0, stream>>>(p, lbl, out, n);
}

// Round 4
// 62.479 us; speedup vs baseline: 1.0792x; 1.0152x over previous
//
#include <hip/hip_runtime.h>

#define NCLS 10
#define NT 512            // 8 waves = 2/SIMD: halves main-loop VALU wall vs 4 waves
#define NWAVES (NT / 64)

// Closed-form contrastive loss:
//   loss = 4 * sum_c (n_c*Q_c - S_c^2) - 2 * (N*Q - S^2)
// with S_c/Q_c/n_c the per-class sum, sum-of-squares, count.
__global__ __launch_bounds__(NT) void closs_kernel(
        const float* __restrict__ p, const int* __restrict__ lbl,
        float* __restrict__ out, int n) {
    float s[NCLS], q[NCLS];
    unsigned cw[NCLS];     // wave-uniform (ballot/popcount) -> scalar pipe
#pragma unroll
    for (int k = 0; k < NCLS; ++k) { s[k] = 0.f; q[k] = 0.f; cw[k] = 0u; }

    const int tid = threadIdx.x;

    // 4 iterations x float4/int4 per thread (N=8192 = 512*4*4), coalesced 16 B/lane.
#pragma unroll
    for (int j = 0; j < 4; ++j) {
        const int e = (j * NT + tid) * 4;
        if (e + 3 < n) {
            const float4 v4 = *reinterpret_cast<const float4*>(p + e);
            const int4   c4 = *reinterpret_cast<const int4*>(lbl + e);
            const float v[4] = {v4.x, v4.y, v4.z, v4.w};
            const int   c[4] = {c4.x, c4.y, c4.z, c4.w};
#pragma unroll
            for (int u = 0; u < 4; ++u) {
#pragma unroll
                for (int k = 0; k < NCLS; ++k) {
                    const bool m = (c[u] == k);
                    const float t = m ? v[u] : 0.f;     // cmp + cndmask
                    s[k] += t;                          // add
                    q[k] = fmaf(t, v[u], q[k]);         // fma  (t*v == v*v when m)
                    cw[k] += (unsigned)__popcll(__ballot(m));  // scalar pipe
                }
            }
        }
    }

    // Butterfly reduce the 20 float accumulators across each 64-lane wave.
#pragma unroll
    for (int k = 0; k < NCLS; ++k) {
#pragma unroll
        for (int off = 32; off > 0; off >>= 1) {
            s[k] += __shfl_xor(s[k], off);
            q[k] += __shfl_xor(q[k], off);
        }
    }

    __shared__ float redf[NWAVES][2 * NCLS];
    __shared__ unsigned redc[NWAVES][NCLS];
    const int wave = tid >> 6;
    const int lane = tid & 63;
    if (lane == 0) {
#pragma unroll
        for (int k = 0; k < NCLS; ++k) {
            redf[wave][k]        = s[k];
            redf[wave][NCLS + k] = q[k];
            redc[wave][k]        = cw[k];
        }
    }
    __syncthreads();

    if (tid == 0) {
        float S = 0.f, Q = 0.f, acc = 0.f;
#pragma unroll
        for (int k = 0; k < NCLS; ++k) {
            float sk = 0.f, qk = 0.f, nk = 0.f;
            for (int w = 0; w < NWAVES; ++w) {
                sk += redf[w][k];
                qk += redf[w][NCLS + k];
                nk += (float)redc[w][k];
            }
            S += sk;
            Q += qk;
            acc += nk * qk - sk * sk;
        }
        const float fn = (float)n;
        out[0] = 4.0f * acc - 2.0f * (fn * Q - S * S);
    }
}

extern "C" void kernel_launch(void* const* d_in, const int* in_sizes, int n_in,
                              void* d_out, int out_size, void* d_ws, size_t ws_size,
                              hipStream_t stream) {
    const float* p = (const float*)d_in[0];
    const int* lbl = (const int*)d_in[1];
    float* out     = (float*)d_out;
    const int n    = in_sizes[0];
    closs_kernel<<<1, NT, 0, stream>>>(p, lbl, out, n);
}